// Round 6
// baseline (473.720 us; speedup 1.0000x reference)
//
#include <hip/hip_runtime.h>
#include <hip/hip_bf16.h>
#include <cstdint>

// Problem constants (ViT-Base, 14x14 window + CLS)
#define BATCH 128
#define NTOK  197
#define NHEAD 12

typedef __attribute__((ext_vector_type(8))) __bf16 bf16x8;
typedef __attribute__((ext_vector_type(4))) float f32x4;
typedef __attribute__((ext_vector_type(4))) unsigned short ushort4v;

#define KSTR 72   // LDS row stride (bf16 elems) for attn P tiles: uniform banks

__device__ __forceinline__ unsigned short f2bf(float f) {
    union { float f; unsigned int u; } v; v.f = f;
    unsigned int r = (v.u + 0x7FFFu + ((v.u >> 16) & 1u)) >> 16;   // RNE
    return (unsigned short)r;
}

// async global->LDS 16B per lane; LDS dest wave-uniform base + lane*16
__device__ __forceinline__ void async_cp16(const void* gsrc, void* lds_dst) {
    __builtin_amdgcn_global_load_lds(
        (const __attribute__((address_space(1))) unsigned int*)((uintptr_t)gsrc),
        (__attribute__((address_space(3))) unsigned int*)((uintptr_t)lds_dst),
        16, 0, 0);
}

// ---------------------------------------------------------------------------
// K0: bias in MFMA C/D fragment order:
//   BT[h][qt16][kt][quad][l16][j*4+r] = rpb[rel_idx[qn][kn]][h]
// ---------------------------------------------------------------------------
__global__ void bias_tiles(const float* __restrict__ rpb,
                           const int* __restrict__ rel_idx,
                           float* __restrict__ BT) {
    int idx = blockIdx.x * 256 + threadIdx.x;          // exactly 786432
    int r    = idx & 3;
    int j    = (idx >> 2) & 3;
    int l16  = (idx >> 4) & 15;
    int quad = (idx >> 8) & 3;
    int kt   = (idx >> 10) & 3;
    int qt   = (idx >> 12) & 15;
    int h    = idx >> 16;                              // 0..11
    int qn = qt * 16 + quad * 4 + r; if (qn > 196) qn = 196;
    int kn = kt * 64 + j * 16 + l16;
    float v = 0.f;
    if (kn < NTOK) v = rpb[rel_idx[qn * NTOK + kn] * NHEAD + h];
    BT[idx] = v;
}

// ---------------------------------------------------------------------------
// fp32 -> bf16 (RNE), vectorized x4
// ---------------------------------------------------------------------------
__global__ __launch_bounds__(256) void cvt_bf16(const float4* __restrict__ src,
                                                ushort4v* __restrict__ dst, int n4) {
    int i = blockIdx.x * 256 + threadIdx.x;
    if (i >= n4) return;
    float4 f = src[i];
    ushort4v o;
    o.x = f2bf(f.x); o.y = f2bf(f.y); o.z = f2bf(f.z); o.w = f2bf(f.w);
    dst[i] = o;
}

// zero helper (vt padding must be 0.0bf16, not uninit bits)
__global__ __launch_bounds__(256) void zero_buf(uint4* __restrict__ p, int n) {
    int i = blockIdx.x * 256 + threadIdx.x;
    if (i < n) p[i] = (uint4){0u, 0u, 0u, 0u};
}

// ---------------------------------------------------------------------------
// bf16 MFMA NT GEMM: 128x128 tile, 4 waves, m97 2-barrier schedule
// (R5-proven on this shape), BK=64 -> 128B LDS rows.
// Bank-conflict-free frag reads (R1/R2-verified, measured 0 conflicts):
//   LDS [row][slot] with slot = chunk ^ (row&7); pre-swizzled global source
//   (global_load_lds writes linearly); read slot = (kk*4+quad) ^ (l16&7)
//   -> each aligned 8-lane group covers all 8 16B granules of the 128B
//   bank space. (R5's 64B rows could NOT be conflict-free: granule =
//   4*(row&1)+slot spans only 4 slots -> 1.089e7 conflicts, 19.5% ceiling.)
// + T1 bijective XCD swizzle (R2-verified: FETCH -62%).
// EPI=0: +qkv bias, q*=0.125 -> q,k scatter [Bc,H,N,64]; v -> TRANSPOSED
//        vt [Bc,H,64,256] (tok padded to 256, pad pre-zeroed).
// EPI=1: +proj bias -> fp32 out [m][768]
// ---------------------------------------------------------------------------
template <int EPI>
__global__ __launch_bounds__(256) void gemm_mfma(
    const unsigned short* __restrict__ A,   // [Mc][768] bf16
    const unsigned short* __restrict__ W,   // [Nn][768] bf16
    const float* __restrict__ bias1, const float* __restrict__ bias2,
    unsigned short* __restrict__ oq, unsigned short* __restrict__ ok,
    unsigned short* __restrict__ ov,        // EPI=0: vt [Bc*H*64][256]
    float* __restrict__ outf,
    int Mc) {
    __shared__ unsigned short As[128 * 64];   // 16 KiB, rows = 128 B
    __shared__ unsigned short Bs[128 * 64];   // 16 KiB

    const int t    = threadIdx.x;
    const int lane = t & 63;
    const int wave = t >> 6;
    const int wm   = wave >> 1;
    const int wn   = wave & 1;
    const int quad = lane >> 4;
    const int l16  = lane & 15;

    // ---- T1: bijective XCD-aware block swizzle (m204) ----
    const int gx  = gridDim.x;
    const int nwg = gx * gridDim.y;
    const int orig = blockIdx.y * gx + blockIdx.x;
    const int q8 = nwg >> 3, r8 = nwg & 7;
    const int xcd = orig & 7, rest = orig >> 3;
    const int wg = (xcd < r8 ? xcd * (q8 + 1) : r8 * (q8 + 1) + (xcd - r8) * q8) + rest;
    const int m0 = (wg / gx) * 128;
    const int n0 = (wg % gx) * 128;

    // ---- staging: instr i covers tile rows i*32 + wave*8 + (lane>>3);
    //      LDS slot = lane&7 (linear dest); global chunk = slot ^ (row&7)
    //      with row&7 == lane>>3 (bases are multiples of 8).
    const int srow8 = lane >> 3;                      // 0..7
    const int chunk = ((lane & 7) ^ srow8) * 8;       // global k-elem offset
    const unsigned short* Ag[4];
    const unsigned short* Bg[4];
#pragma unroll
    for (int i = 0; i < 4; i++) {
        int ra = m0 + i * 32 + wave * 8 + srow8; if (ra >= Mc) ra = Mc - 1;
        Ag[i] = A + (size_t)ra * 768 + chunk;
        Bg[i] = W + (size_t)(n0 + i * 32 + wave * 8 + srow8) * 768 + chunk;
    }

    // frag read bases: row = wm*64 + i2*16 + l16 (row&7 == l16&7),
    // slot = (kk*4+quad) ^ (l16&7) -> 8-lane groups cover all 8 granules
    const int x7 = l16 & 7;
    const unsigned short* Afp0 = As + (wm * 64 + l16) * 64 + ((quad ^ x7) * 8);
    const unsigned short* Afp1 = As + (wm * 64 + l16) * 64 + (((4 + quad) ^ x7) * 8);
    const unsigned short* Bfp0 = Bs + (wn * 64 + l16) * 64 + ((quad ^ x7) * 8);
    const unsigned short* Bfp1 = Bs + (wn * 64 + l16) * 64 + (((4 + quad) ^ x7) * 8);

    f32x4 acc[4][4] = {};

    for (int k0 = 0; k0 < 768; k0 += 64) {
        __syncthreads();                       // prev step's reads complete
#pragma unroll
        for (int i = 0; i < 4; i++) {
            async_cp16(Ag[i] + k0, As + i * 2048 + wave * 512);
            async_cp16(Bg[i] + k0, Bs + i * 2048 + wave * 512);
        }
        __syncthreads();                       // compiler drains vmcnt before barrier
#pragma unroll
        for (int kk = 0; kk < 2; kk++) {
            const unsigned short* Af = kk ? Afp1 : Afp0;
            const unsigned short* Bf = kk ? Bfp1 : Bfp0;
            bf16x8 af[4], bfr[4];
#pragma unroll
            for (int i = 0; i < 4; i++) af[i]  = *(const bf16x8*)(Af + i * 16 * 64);
#pragma unroll
            for (int j = 0; j < 4; j++) bfr[j] = *(const bf16x8*)(Bf + j * 16 * 64);
#pragma unroll
            for (int i = 0; i < 4; i++)
#pragma unroll
                for (int j = 0; j < 4; j++)
                    acc[i][j] = __builtin_amdgcn_mfma_f32_16x16x32_bf16(
                        af[i], bfr[j], acc[i][j], 0, 0, 0);
        }
    }

    if (EPI == 0) {
        const int part = n0 / 768;
        const int nb0  = n0 - part * 768;
        if (part < 2) {
            const float scale = (part == 0) ? 0.125f : 1.f;
            unsigned short* dst = (part == 0) ? oq : ok;
#pragma unroll
            for (int j = 0; j < 4; j++) {
                const int nnb = nb0 + wn * 64 + j * 16;
                const int h   = nnb >> 6;
                const int d   = (nnb & 63) + l16;
                const float bb = (part == 0) ? bias1[nnb + l16] : 0.f;
#pragma unroll
                for (int i = 0; i < 4; i++) {
                    const int mb = m0 + wm * 64 + i * 16 + quad * 4;
#pragma unroll
                    for (int r = 0; r < 4; r++) {
                        const int m = mb + r;
                        if (m < Mc) {
                            const int bi  = m / NTOK;
                            const int tok = m - bi * NTOK;
                            dst[(((size_t)bi * NHEAD + h) * NTOK + tok) * 64 + d] =
                                f2bf((acc[i][j][r] + bb) * scale);
                        }
                    }
                }
            }
        } else {   // v -> transposed vt[(bi*12+h)*64 + d][256]
#pragma unroll
            for (int j = 0; j < 4; j++) {
                const int nnb = nb0 + wn * 64 + j * 16;
                const int h   = nnb >> 6;
                const int d   = (nnb & 63) + l16;
                const float bb = bias2[nnb + l16];
#pragma unroll
                for (int i = 0; i < 4; i++) {
                    const int mb = m0 + wm * 64 + i * 16 + quad * 4;
#pragma unroll
                    for (int r = 0; r < 4; r++) {
                        const int m = mb + r;
                        if (m < Mc) {
                            const int bi  = m / NTOK;
                            const int tok = m - bi * NTOK;
                            ov[(((size_t)bi * NHEAD + h) * 64 + d) * 256 + tok] =
                                f2bf(acc[i][j][r] + bb);
                        }
                    }
                }
            }
        }
    } else {
#pragma unroll
        for (int j = 0; j < 4; j++) {
            const int col = n0 + wn * 64 + j * 16 + l16;
            const float bb = bias1[col];
#pragma unroll
            for (int i = 0; i < 4; i++) {
                const int mb = m0 + wm * 64 + i * 16 + quad * 4;
#pragma unroll
                for (int r = 0; r < 4; r++) {
                    const int m = mb + r;
                    if (m < Mc) outf[(size_t)m * 768 + col] = acc[i][j][r] + bb;
                }
            }
        }
    }
}

// ---------------------------------------------------------------------------
// K2: MFMA flash attention (R5-verified, unchanged). One block per (b,h);
// 4 waves x 64 q-rows. K and V^T tiles staged via global_load_lds into
// [64][64] LDS with XOR bank swizzle. V pre-transposed by the QKV GEMM.
// ---------------------------------------------------------------------------
__global__ __launch_bounds__(256, 2) void attn_mfma(
    const unsigned short* __restrict__ Q, const unsigned short* __restrict__ K,
    const unsigned short* __restrict__ VT, const float* __restrict__ BT,
    unsigned short* __restrict__ AO) {
    __shared__ unsigned short Ks[64 * 64];         // K-tile  [key][d]   (swz)
    __shared__ unsigned short Vt[64 * 64];         // V-tile^T [d][key]  (swz)
    __shared__ unsigned short Ps[4][64 * KSTR];    // per-wave P [q][key]

    const int t    = threadIdx.x;
    const int lane = t & 63;
    const int wave = t >> 6;
    const int quad = lane >> 4;
    const int l16  = lane & 15;
    const int bh   = blockIdx.x;
    const int b    = bh / NHEAD;
    const int h    = bh - b * NHEAD;

    const unsigned short* qb  = Q  + (size_t)bh * NTOK * 64;
    const unsigned short* kb  = K  + (size_t)bh * NTOK * 64;
    const unsigned short* vtg = VT + (size_t)bh * 64 * 256;

    // Q fragments in registers for the whole kernel (A-layout: m=l16, k=quad*8+j)
    bf16x8 qf[4][2];
#pragma unroll
    for (int i = 0; i < 4; i++) {
        int tok = wave * 64 + i * 16 + l16; if (tok > 196) tok = 196;
#pragma unroll
        for (int ks = 0; ks < 2; ks++)
            qf[i][ks] = *(const bf16x8*)&qb[(size_t)tok * 64 + ks * 32 + quad * 8];
    }

    f32x4 O[4][4] = {};
    float lsum[4][4] = {};        // [i][r]

    for (int kt = 0; kt < 4; kt++) {
        __syncthreads();          // prior iteration's Ks/Vt reads complete
        {   // async stage: rows = wave*8 + (lane>>3) (+32 for 2nd instr);
            // LDS linear [row][slot=lane&7]; global chunk = slot ^ (row&7)
            const int rsub = wave * 8 + (lane >> 3);
            const int chk  = ((lane & 7) ^ (lane >> 3)) * 8;     // elems
            int gk0 = kt * 64 + rsub;      if (gk0 > 196) gk0 = 196;
            int gk1 = kt * 64 + 32 + rsub; if (gk1 > 196) gk1 = 196;
            async_cp16(kb + (size_t)gk0 * 64 + chk, Ks + wave * 512);
            async_cp16(kb + (size_t)gk1 * 64 + chk, Ks + 2048 + wave * 512);
            async_cp16(vtg + (size_t)rsub * 256 + kt * 64 + chk, Vt + wave * 512);
            async_cp16(vtg + (size_t)(32 + rsub) * 256 + kt * 64 + chk,
                       Vt + 2048 + wave * 512);
        }

        // ---- acc init = rpb fragments (issued under the async staging) ----
        f32x4 acc[4][4];
#pragma unroll
        for (int i = 0; i < 4; i++) {
            const float4* bp = (const float4*)&BT[
                (((((size_t)h * 16 + (wave * 4 + i)) * 4 + kt) * 4 + quad) * 16 + l16) * 16];
#pragma unroll
            for (int j = 0; j < 4; j++) {
                float4 f = bp[j];
                acc[i][j] = (f32x4){f.x, f.y, f.z, f.w};
            }
        }

        asm volatile("s_waitcnt vmcnt(0)" ::: "memory");
        __builtin_amdgcn_s_barrier();

        // ---- S = q.k^T + bias ----
#pragma unroll
        for (int ks = 0; ks < 2; ks++) {
            bf16x8 kf[4];
#pragma unroll
            for (int j = 0; j < 4; j++)
                kf[j] = *(const bf16x8*)&Ks[(j * 16 + l16) * 64 +
                                            (((ks * 4 + quad) ^ (l16 & 7)) * 8)];
            __builtin_amdgcn_s_setprio(1);
#pragma unroll
            for (int i = 0; i < 4; i++)
#pragma unroll
                for (int j = 0; j < 4; j++)
                    acc[i][j] = __builtin_amdgcn_mfma_f32_16x16x32_bf16(
                        qf[i][ks], kf[j], acc[i][j], 0, 0, 0);
            __builtin_amdgcn_s_setprio(0);
        }

        // ---- fixed-max softmax: p = exp(s), masked keys -> 0; write P ----
#pragma unroll
        for (int j = 0; j < 4; j++) {
            const int kn = kt * 64 + j * 16 + l16;
            const bool kval = (kn < NTOK);
#pragma unroll
            for (int i = 0; i < 4; i++)
#pragma unroll
                for (int r = 0; r < 4; r++) {
                    float p = kval ? __expf(fminf(acc[i][j][r], 30.f)) : 0.f;
                    lsum[i][r] += p;
                    Ps[wave][(i * 16 + quad * 4 + r) * KSTR + j * 16 + l16] = f2bf(p);
                }
        }
        // in-wave LDS write->read ordering: compiler inserts lgkmcnt; no barrier
        // needed (Ps[wave] is wave-private).

        // ---- O += P.V ----
#pragma unroll
        for (int ks = 0; ks < 2; ks++) {
            bf16x8 vf[4], pf[4];
#pragma unroll
            for (int jd = 0; jd < 4; jd++)
                vf[jd] = *(const bf16x8*)&Vt[(jd * 16 + l16) * 64 +
                                             (((ks * 4 + quad) ^ (l16 & 7)) * 8)];
#pragma unroll
            for (int i = 0; i < 4; i++)
                pf[i] = *(const bf16x8*)&Ps[wave][(i * 16 + l16) * KSTR + ks * 32 + quad * 8];
            __builtin_amdgcn_s_setprio(1);
#pragma unroll
            for (int i = 0; i < 4; i++)
#pragma unroll
                for (int jd = 0; jd < 4; jd++)
                    O[i][jd] = __builtin_amdgcn_mfma_f32_16x16x32_bf16(
                        pf[i], vf[jd], O[i][jd], 0, 0, 0);
            __builtin_amdgcn_s_setprio(0);
        }
    }

    // ---- l-sum reduction across the 16-lane col groups, then store ----
#pragma unroll
    for (int i = 0; i < 4; i++)
#pragma unroll
        for (int r = 0; r < 4; r++) {
            float l = lsum[i][r];
            l += __shfl_xor(l, 1); l += __shfl_xor(l, 2);
            l += __shfl_xor(l, 4); l += __shfl_xor(l, 8);
            lsum[i][r] = 1.f / l;
        }
#pragma unroll
    for (int i = 0; i < 4; i++) {
        const int tb = wave * 64 + i * 16 + quad * 4;
#pragma unroll
        for (int r = 0; r < 4; r++) {
            const int tok = tb + r;
            if (tok < NTOK) {
                const float rl = lsum[i][r];
#pragma unroll
                for (int jd = 0; jd < 4; jd++)
                    AO[((size_t)b * NTOK + tok) * 768 + h * 64 + jd * 16 + l16] =
                        f2bf(O[i][jd][r] * rl);
            }
        }
    }
}

// ---------------------------------------------------------------------------
extern "C" void kernel_launch(void* const* d_in, const int* in_sizes, int n_in,
                              void* d_out, int out_size, void* d_ws, size_t ws_size,
                              hipStream_t stream) {
    const float* x      = (const float*)d_in[0];
    const float* qkv_w  = (const float*)d_in[1];
    const float* q_bias = (const float*)d_in[2];
    const float* v_bias = (const float*)d_in[3];
    const float* rpb    = (const float*)d_in[4];
    const float* proj_w = (const float*)d_in[5];
    const float* proj_b = (const float*)d_in[6];
    const int*   rel_idx = (const int*)d_in[7];
    float* out = (float*)d_out;

    const size_t EB   = 151296;                    // 12*197*64 = 197*768
    const size_t VTE  = 196608;                    // 12*64*256 (vt elems/batch)
    const size_t NBT  = 786432;                    // bias tiles (floats)
    const size_t NX   = (size_t)BATCH * NTOK * 768;
    const size_t NWQ  = (size_t)2304 * 768;
    const size_t NWP  = (size_t)768 * 768;

    // layout: BT(f32) | xbf | wqkv | wproj | q,k (EB) | vt (VTE) | ao (EB)
    const size_t fixed_bytes = NBT * 4 + (NX + NWQ + NWP) * 2;
    const size_t per_b = 2ull * (3 * EB + VTE);    // bytes per batch elem
    int Bc = BATCH;
    while (Bc > 1 && fixed_bytes + (size_t)Bc * per_b > ws_size) Bc >>= 1;
    if (fixed_bytes + (size_t)Bc * per_b > ws_size) return;
    const int nc = BATCH / Bc;
    const int Mc = Bc * NTOK;
    const int Gy = (Mc + 127) / 128;

    float* BT             = (float*)d_ws;
    unsigned short* xbf   = (unsigned short*)(BT + NBT);
    unsigned short* wqkv  = xbf + NX;
    unsigned short* wproj = wqkv + NWQ;
    unsigned short* q     = wproj + NWP;
    unsigned short* k     = q + (size_t)Bc * EB;
    unsigned short* vt    = k + (size_t)Bc * EB;
    unsigned short* aobf  = vt + (size_t)Bc * VTE;

    const int nz = Bc * 24576;                     // vt bytes / 16
    zero_buf<<<(nz + 255) / 256, 256, 0, stream>>>((uint4*)vt, nz);
    bias_tiles<<<(int)(NBT / 256), 256, 0, stream>>>(rpb, rel_idx, BT);
    cvt_bf16<<<(int)((NX / 4 + 255) / 256), 256, 0, stream>>>(
        (const float4*)x, (ushort4v*)xbf, (int)(NX / 4));
    cvt_bf16<<<(int)((NWQ / 4 + 255) / 256), 256, 0, stream>>>(
        (const float4*)qkv_w, (ushort4v*)wqkv, (int)(NWQ / 4));
    cvt_bf16<<<(int)((NWP / 4 + 255) / 256), 256, 0, stream>>>(
        (const float4*)proj_w, (ushort4v*)wproj, (int)(NWP / 4));

    for (int c = 0; c < nc; c++) {
        gemm_mfma<0><<<dim3(2304 / 128, Gy), 256, 0, stream>>>(
            xbf + (size_t)c * Mc * 768, wqkv, q_bias, v_bias, q, k, vt, nullptr, Mc);
        attn_mfma<<<Bc * NHEAD, 256, 0, stream>>>(q, k, vt, BT, aobf);
        gemm_mfma<1><<<dim3(768 / 128, Gy), 256, 0, stream>>>(
            aobf, wproj, proj_b, nullptr, nullptr, nullptr, nullptr,
            out + (size_t)c * Mc * 768, Mc);
    }
}

// Round 7
// 456.324 us; speedup vs baseline: 1.0381x; 1.0381x over previous
//
#include <hip/hip_runtime.h>
#include <hip/hip_bf16.h>
#include <cstdint>

// Problem constants (ViT-Base, 14x14 window + CLS)
#define BATCH 128
#define NTOK  197
#define NHEAD 12

typedef __attribute__((ext_vector_type(8))) __bf16 bf16x8;
typedef __attribute__((ext_vector_type(4))) float f32x4;
typedef __attribute__((ext_vector_type(4))) unsigned short ushort4v;

#define KSTR 72   // LDS row stride (bf16 elems) for attn P tiles: uniform banks

__device__ __forceinline__ unsigned short f2bf(float f) {
    union { float f; unsigned int u; } v; v.f = f;
    unsigned int r = (v.u + 0x7FFFu + ((v.u >> 16) & 1u)) >> 16;   // RNE
    return (unsigned short)r;
}

// async global->LDS 16B per lane; LDS dest wave-uniform base + lane*16
__device__ __forceinline__ void async_cp16(const void* gsrc, void* lds_dst) {
    __builtin_amdgcn_global_load_lds(
        (const __attribute__((address_space(1))) unsigned int*)((uintptr_t)gsrc),
        (__attribute__((address_space(3))) unsigned int*)((uintptr_t)lds_dst),
        16, 0, 0);
}

// ---------------------------------------------------------------------------
// K0: bias in MFMA C/D fragment order:
//   BT[h][qt16][kt][quad][l16][j*4+r] = rpb[rel_idx[qn][kn]][h]
// Masked keys (kn >= NTOK) get -1e30 so attn's exp() yields 0 directly
// (removes the per-element mask select in the softmax hot loop).
// ---------------------------------------------------------------------------
__global__ void bias_tiles(const float* __restrict__ rpb,
                           const int* __restrict__ rel_idx,
                           float* __restrict__ BT) {
    int idx = blockIdx.x * 256 + threadIdx.x;          // exactly 786432
    int r    = idx & 3;
    int j    = (idx >> 2) & 3;
    int l16  = (idx >> 4) & 15;
    int quad = (idx >> 8) & 3;
    int kt   = (idx >> 10) & 3;
    int qt   = (idx >> 12) & 15;
    int h    = idx >> 16;                              // 0..11
    int qn = qt * 16 + quad * 4 + r; if (qn > 196) qn = 196;
    int kn = kt * 64 + j * 16 + l16;
    float v = -1e30f;
    if (kn < NTOK) v = rpb[rel_idx[qn * NTOK + kn] * NHEAD + h];
    BT[idx] = v;
}

// ---------------------------------------------------------------------------
// fp32 -> bf16 (RNE), vectorized x4
// ---------------------------------------------------------------------------
__global__ __launch_bounds__(256) void cvt_bf16(const float4* __restrict__ src,
                                                ushort4v* __restrict__ dst, int n4) {
    int i = blockIdx.x * 256 + threadIdx.x;
    if (i >= n4) return;
    float4 f = src[i];
    ushort4v o;
    o.x = f2bf(f.x); o.y = f2bf(f.y); o.z = f2bf(f.z); o.w = f2bf(f.w);
    dst[i] = o;
}

// zero helper (vt padding must be 0.0bf16, not uninit bits)
__global__ __launch_bounds__(256) void zero_buf(uint4* __restrict__ p, int n) {
    int i = blockIdx.x * 256 + threadIdx.x;
    if (i < n) p[i] = (uint4){0u, 0u, 0u, 0u};
}

// ---------------------------------------------------------------------------
// bf16 MFMA NT GEMM: 128x128 tile, 4 waves, m97 2-barrier schedule, BK=32.
// LDS 16 KiB (R5's occupancy ~29%) with CONFLICT-FREE pair-of-rows layout
// (R3-verified addressing): two m-rows share a 128B LDS line,
//   addr(row,chunk) = (row>>1)*64 + (row&1)*32 + ((chunk ^ ((row>>1)&3))*8)
// An 8-lane frag read (rows r0..r0+7) hits granules {par*4 + chunk^line&3}
// = all 8 16B granules of the 128B bank space -> only 2-way alias (free).
// Staging pre-swizzles the GLOBAL source (global_load_lds dest is linear):
//   thread t, instr i: row = i*64 + 2*(t>>3) + ((t>>2)&1),
//                      chunk = (t&3) ^ ((t>>3)&3).
// + T1 bijective XCD swizzle (R2-verified: FETCH -62%).
// Epilogue: no per-element integer division (incremental tok/bi).
// EPI=0: +qkv bias, q*=0.125 -> q,k scatter [Bc,H,N,64]; v -> TRANSPOSED
//        vt [Bc,H,64,256] (tok padded to 256, pad pre-zeroed).
// EPI=1: +proj bias -> fp32 out [m][768]
// ---------------------------------------------------------------------------
template <int EPI>
__global__ __launch_bounds__(256) void gemm_mfma(
    const unsigned short* __restrict__ A,   // [Mc][768] bf16
    const unsigned short* __restrict__ W,   // [Nn][768] bf16
    const float* __restrict__ bias1, const float* __restrict__ bias2,
    unsigned short* __restrict__ oq, unsigned short* __restrict__ ok,
    unsigned short* __restrict__ ov,        // EPI=0: vt [Bc*H*64][256]
    float* __restrict__ outf,
    int Mc) {
    __shared__ unsigned short As[128 * 32];   // 8 KiB, pair-of-rows layout
    __shared__ unsigned short Bs[128 * 32];   // 8 KiB

    const int t    = threadIdx.x;
    const int lane = t & 63;
    const int wave = t >> 6;
    const int wm   = wave >> 1;
    const int wn   = wave & 1;
    const int quad = lane >> 4;
    const int l16  = lane & 15;

    // ---- T1: bijective XCD-aware block swizzle (m204) ----
    const int gx  = gridDim.x;
    const int nwg = gx * gridDim.y;
    const int orig = blockIdx.y * gx + blockIdx.x;
    const int q8 = nwg >> 3, r8 = nwg & 7;
    const int xcd = orig & 7, rest = orig >> 3;
    const int wg = (xcd < r8 ? xcd * (q8 + 1) : r8 * (q8 + 1) + (xcd - r8) * q8) + rest;
    const int m0 = (wg / gx) * 128;
    const int n0 = (wg % gx) * 128;

    // ---- staging lane geometry (R3-verified; spot-check: A[5][chunk1] ->
    //      thread 23 -> LDS elem 184 == read addr(5,1) = 184) ----
    const int grow = wave * 16 + ((lane >> 3) << 1) + ((lane >> 2) & 1);
    const int kcol = (((lane & 3) ^ ((lane >> 3) & 3)) << 3);    // elems
    const unsigned short* Ag[2];
    const unsigned short* Bg[2];
#pragma unroll
    for (int i = 0; i < 2; i++) {
        int ra = m0 + i * 64 + grow; if (ra >= Mc) ra = Mc - 1;
        Ag[i] = A + (size_t)ra * 768 + kcol;
        Bg[i] = W + (size_t)(n0 + i * 64 + grow) * 768 + kcol;
    }

    // ---- frag read bases: row = base16 + l16 -> line&3 = (l16>>1)&3 ----
    const int l2  = l16 >> 1;
    const int par = l16 & 1;
    const int xr  = l2 & 3;
    const unsigned short* Afp = As + (wm * 32 + l2) * 64 + par * 32 + ((quad ^ xr) << 3);
    const unsigned short* Bfp = Bs + (wn * 32 + l2) * 64 + par * 32 + ((quad ^ xr) << 3);

    f32x4 acc[4][4] = {};

    for (int k0 = 0; k0 < 768; k0 += 32) {
        __syncthreads();
        async_cp16(Ag[0] + k0, As + wave * 512);
        async_cp16(Ag[1] + k0, As + 2048 + wave * 512);
        async_cp16(Bg[0] + k0, Bs + wave * 512);
        async_cp16(Bg[1] + k0, Bs + 2048 + wave * 512);
        __syncthreads();
        bf16x8 af[4], bfr[4];
#pragma unroll
        for (int i = 0; i < 4; i++) af[i]  = *(const bf16x8*)(Afp + i * 512);
#pragma unroll
        for (int j = 0; j < 4; j++) bfr[j] = *(const bf16x8*)(Bfp + j * 512);
#pragma unroll
        for (int i = 0; i < 4; i++)
#pragma unroll
            for (int j = 0; j < 4; j++)
                acc[i][j] = __builtin_amdgcn_mfma_f32_16x16x32_bf16(
                    af[i], bfr[j], acc[i][j], 0, 0, 0);
    }

    // ---- epilogue: C/D col = l16 (n), row = quad*4+r (m); no int div ----
    if (EPI == 0) {
        const int part = n0 / 768;
        const int nb0  = n0 - part * 768;
        const int bi0  = m0 / NTOK;            // block-uniform (scalar)
        const int tk0  = m0 - bi0 * NTOK;
        if (part < 2) {
            const float scale = (part == 0) ? 0.125f : 1.f;
            unsigned short* dst = (part == 0) ? oq : ok;
#pragma unroll
            for (int j = 0; j < 4; j++) {
                const int nnb = nb0 + wn * 64 + j * 16;
                const int h   = nnb >> 6;
                const int d   = (nnb & 63) + l16;
                const float bb = (part == 0) ? bias1[nnb + l16] : 0.f;
#pragma unroll
                for (int i = 0; i < 4; i++) {
                    const int off = wm * 64 + i * 16 + quad * 4;
#pragma unroll
                    for (int r = 0; r < 4; r++) {
                        const int m = m0 + off + r;
                        if (m < Mc) {
                            int tok = tk0 + off + r;
                            int bi  = bi0;
                            if (tok >= NTOK) { tok -= NTOK; bi++; }
                            dst[(((size_t)bi * NHEAD + h) * NTOK + tok) * 64 + d] =
                                f2bf((acc[i][j][r] + bb) * scale);
                        }
                    }
                }
            }
        } else {   // v -> transposed vt[(bi*12+h)*64 + d][256]
#pragma unroll
            for (int j = 0; j < 4; j++) {
                const int nnb = nb0 + wn * 64 + j * 16;
                const int h   = nnb >> 6;
                const int d   = (nnb & 63) + l16;
                const float bb = bias2[nnb + l16];
#pragma unroll
                for (int i = 0; i < 4; i++) {
                    const int off = wm * 64 + i * 16 + quad * 4;
#pragma unroll
                    for (int r = 0; r < 4; r++) {
                        const int m = m0 + off + r;
                        if (m < Mc) {
                            int tok = tk0 + off + r;
                            int bi  = bi0;
                            if (tok >= NTOK) { tok -= NTOK; bi++; }
                            ov[(((size_t)bi * NHEAD + h) * 64 + d) * 256 + tok] =
                                f2bf(acc[i][j][r] + bb);
                        }
                    }
                }
            }
        }
    } else {
#pragma unroll
        for (int j = 0; j < 4; j++) {
            const int col = n0 + wn * 64 + j * 16 + l16;
            const float bb = bias1[col];
#pragma unroll
            for (int i = 0; i < 4; i++) {
                const int mb = m0 + wm * 64 + i * 16 + quad * 4;
#pragma unroll
                for (int r = 0; r < 4; r++) {
                    const int m = mb + r;
                    if (m < Mc) outf[(size_t)m * 768 + col] = acc[i][j][r] + bb;
                }
            }
        }
    }
}

// ---------------------------------------------------------------------------
// K2: MFMA flash attention. One block per (b,h); 4 waves x 64 q-rows.
// NEW: K/V tiles DOUBLE-BUFFERED; next tile's 4 global_load_lds issued at
// the top of each tile so the single vmcnt(0)+barrier (at tile end) drains
// loads that had ~2000 cycles of QK^T/softmax/PV to complete under.
// Staging addressing unchanged (R5/R6-verified, 0 conflicts). Key mask is
// folded into BT (-1e30 -> exp -> 0), removing the softmax select.
// ---------------------------------------------------------------------------
__global__ __launch_bounds__(256, 2) void attn_mfma(
    const unsigned short* __restrict__ Q, const unsigned short* __restrict__ K,
    const unsigned short* __restrict__ VT, const float* __restrict__ BT,
    unsigned short* __restrict__ AO) {
    __shared__ unsigned short Ks[2][64 * 64];      // K-tile  [key][d]   (swz)
    __shared__ unsigned short Vt[2][64 * 64];      // V-tile^T [d][key]  (swz)
    __shared__ unsigned short Ps[4][64 * KSTR];    // per-wave P [q][key]

    const int t    = threadIdx.x;
    const int lane = t & 63;
    const int wave = t >> 6;
    const int quad = lane >> 4;
    const int l16  = lane & 15;
    const int bh   = blockIdx.x;
    const int b    = bh / NHEAD;
    const int h    = bh - b * NHEAD;

    const unsigned short* qb  = Q  + (size_t)bh * NTOK * 64;
    const unsigned short* kb  = K  + (size_t)bh * NTOK * 64;
    const unsigned short* vtg = VT + (size_t)bh * 64 * 256;

    // staging lane geometry (R5-verified)
    const int rsub = wave * 8 + (lane >> 3);
    const int chk  = ((lane & 7) ^ (lane >> 3)) * 8;         // elems

    auto stage = [&](int buf, int kt) {
        int gk0 = kt * 64 + rsub;      if (gk0 > 196) gk0 = 196;
        int gk1 = kt * 64 + 32 + rsub; if (gk1 > 196) gk1 = 196;
        async_cp16(kb + (size_t)gk0 * 64 + chk, Ks[buf] + wave * 512);
        async_cp16(kb + (size_t)gk1 * 64 + chk, Ks[buf] + 2048 + wave * 512);
        async_cp16(vtg + (size_t)rsub * 256 + kt * 64 + chk, Vt[buf] + wave * 512);
        async_cp16(vtg + (size_t)(32 + rsub) * 256 + kt * 64 + chk,
                   Vt[buf] + 2048 + wave * 512);
    };

    // Q fragments in registers for the whole kernel (A-layout: m=l16, k=quad*8+j)
    bf16x8 qf[4][2];
#pragma unroll
    for (int i = 0; i < 4; i++) {
        int tok = wave * 64 + i * 16 + l16; if (tok > 196) tok = 196;
#pragma unroll
        for (int ks = 0; ks < 2; ks++)
            qf[i][ks] = *(const bf16x8*)&qb[(size_t)tok * 64 + ks * 32 + quad * 8];
    }

    f32x4 O[4][4] = {};
    float lsum[4][4] = {};        // [i][r]

    stage(0, 0);
    asm volatile("s_waitcnt vmcnt(0)" ::: "memory");
    __builtin_amdgcn_s_barrier();

    for (int kt = 0; kt < 4; kt++) {
        const int buf = kt & 1;

        // ---- acc init = rpb fragments (issued BEFORE the prefetch so the
        //      compiler's wait for them need not drain the prefetch) ----
        f32x4 acc[4][4];
#pragma unroll
        for (int i = 0; i < 4; i++) {
            const float4* bp = (const float4*)&BT[
                (((((size_t)h * 16 + (wave * 4 + i)) * 4 + kt) * 4 + quad) * 16 + l16) * 16];
#pragma unroll
            for (int j = 0; j < 4; j++) {
                float4 f = bp[j];
                acc[i][j] = (f32x4){f.x, f.y, f.z, f.w};
            }
        }

        if (kt < 3) stage(buf ^ 1, kt + 1);   // prefetch under this tile's compute

        // ---- S = q.k^T + bias ----
#pragma unroll
        for (int ks = 0; ks < 2; ks++) {
            bf16x8 kf[4];
#pragma unroll
            for (int j = 0; j < 4; j++)
                kf[j] = *(const bf16x8*)&Ks[buf][(j * 16 + l16) * 64 +
                                               (((ks * 4 + quad) ^ (l16 & 7)) * 8)];
            __builtin_amdgcn_s_setprio(1);
#pragma unroll
            for (int i = 0; i < 4; i++)
#pragma unroll
                for (int j = 0; j < 4; j++)
                    acc[i][j] = __builtin_amdgcn_mfma_f32_16x16x32_bf16(
                        qf[i][ks], kf[j], acc[i][j], 0, 0, 0);
            __builtin_amdgcn_s_setprio(0);
        }

        // ---- fixed-max softmax: p = exp(s) (mask folded into BT) ----
#pragma unroll
        for (int j = 0; j < 4; j++)
#pragma unroll
            for (int i = 0; i < 4; i++)
#pragma unroll
                for (int r = 0; r < 4; r++) {
                    float p = __expf(fminf(acc[i][j][r], 30.f));
                    lsum[i][r] += p;
                    Ps[wave][(i * 16 + quad * 4 + r) * KSTR + j * 16 + l16] = f2bf(p);
                }
        // in-wave LDS write->read ordering: compiler inserts lgkmcnt; no barrier
        // needed (Ps[wave] is wave-private).

        // ---- O += P.V ----
#pragma unroll
        for (int ks = 0; ks < 2; ks++) {
            bf16x8 vf[4], pf[4];
#pragma unroll
            for (int jd = 0; jd < 4; jd++)
                vf[jd] = *(const bf16x8*)&Vt[buf][(jd * 16 + l16) * 64 +
                                                 (((ks * 4 + quad) ^ (l16 & 7)) * 8)];
#pragma unroll
            for (int i = 0; i < 4; i++)
                pf[i] = *(const bf16x8*)&Ps[wave][(i * 16 + l16) * KSTR + ks * 32 + quad * 8];
            __builtin_amdgcn_s_setprio(1);
#pragma unroll
            for (int i = 0; i < 4; i++)
#pragma unroll
                for (int jd = 0; jd < 4; jd++)
                    O[i][jd] = __builtin_amdgcn_mfma_f32_16x16x32_bf16(
                        pf[i], vf[jd], O[i][jd], 0, 0, 0);
            __builtin_amdgcn_s_setprio(0);
        }

        // tile boundary: prefetch (issued ~2000 cyc ago) lands; buffers swap
        asm volatile("s_waitcnt vmcnt(0)" ::: "memory");
        __builtin_amdgcn_s_barrier();
    }

    // ---- l-sum reduction across the 16-lane col groups, then store ----
#pragma unroll
    for (int i = 0; i < 4; i++)
#pragma unroll
        for (int r = 0; r < 4; r++) {
            float l = lsum[i][r];
            l += __shfl_xor(l, 1); l += __shfl_xor(l, 2);
            l += __shfl_xor(l, 4); l += __shfl_xor(l, 8);
            lsum[i][r] = 1.f / l;
        }
#pragma unroll
    for (int i = 0; i < 4; i++) {
        const int tb = wave * 64 + i * 16 + quad * 4;
#pragma unroll
        for (int r = 0; r < 4; r++) {
            const int tok = tb + r;
            if (tok < NTOK) {
                const float rl = lsum[i][r];
#pragma unroll
                for (int jd = 0; jd < 4; jd++)
                    AO[((size_t)b * NTOK + tok) * 768 + h * 64 + jd * 16 + l16] =
                        f2bf(O[i][jd][r] * rl);
            }
        }
    }
}

// ---------------------------------------------------------------------------
extern "C" void kernel_launch(void* const* d_in, const int* in_sizes, int n_in,
                              void* d_out, int out_size, void* d_ws, size_t ws_size,
                              hipStream_t stream) {
    const float* x      = (const float*)d_in[0];
    const float* qkv_w  = (const float*)d_in[1];
    const float* q_bias = (const float*)d_in[2];
    const float* v_bias = (const float*)d_in[3];
    const float* rpb    = (const float*)d_in[4];
    const float* proj_w = (const float*)d_in[5];
    const float* proj_b = (const float*)d_in[6];
    const int*   rel_idx = (const int*)d_in[7];
    float* out = (float*)d_out;

    const size_t EB   = 151296;                    // 12*197*64 = 197*768
    const size_t VTE  = 196608;                    // 12*64*256 (vt elems/batch)
    const size_t NBT  = 786432;                    // bias tiles (floats)
    const size_t NX   = (size_t)BATCH * NTOK * 768;
    const size_t NWQ  = (size_t)2304 * 768;
    const size_t NWP  = (size_t)768 * 768;

    // layout: BT(f32) | xbf | wqkv | wproj | q,k (EB) | vt (VTE) | ao (EB)
    const size_t fixed_bytes = NBT * 4 + (NX + NWQ + NWP) * 2;
    const size_t per_b = 2ull * (3 * EB + VTE);    // bytes per batch elem
    int Bc = BATCH;
    while (Bc > 1 && fixed_bytes + (size_t)Bc * per_b > ws_size) Bc >>= 1;
    if (fixed_bytes + (size_t)Bc * per_b > ws_size) return;
    const int nc = BATCH / Bc;
    const int Mc = Bc * NTOK;
    const int Gy = (Mc + 127) / 128;

    float* BT             = (float*)d_ws;
    unsigned short* xbf   = (unsigned short*)(BT + NBT);
    unsigned short* wqkv  = xbf + NX;
    unsigned short* wproj = wqkv + NWQ;
    unsigned short* q     = wproj + NWP;
    unsigned short* k     = q + (size_t)Bc * EB;
    unsigned short* vt    = k + (size_t)Bc * EB;
    unsigned short* aobf  = vt + (size_t)Bc * VTE;

    const int nz = Bc * 24576;                     // vt bytes / 16
    zero_buf<<<(nz + 255) / 256, 256, 0, stream>>>((uint4*)vt, nz);
    bias_tiles<<<(int)(NBT / 256), 256, 0, stream>>>(rpb, rel_idx, BT);
    cvt_bf16<<<(int)((NX / 4 + 255) / 256), 256, 0, stream>>>(
        (const float4*)x, (ushort4v*)xbf, (int)(NX / 4));
    cvt_bf16<<<(int)((NWQ / 4 + 255) / 256), 256, 0, stream>>>(
        (const float4*)qkv_w, (ushort4v*)wqkv, (int)(NWQ / 4));
    cvt_bf16<<<(int)((NWP / 4 + 255) / 256), 256, 0, stream>>>(
        (const float4*)proj_w, (ushort4v*)wproj, (int)(NWP / 4));

    for (int c = 0; c < nc; c++) {
        gemm_mfma<0><<<dim3(2304 / 128, Gy), 256, 0, stream>>>(
            xbf + (size_t)c * Mc * 768, wqkv, q_bias, v_bias, q, k, vt, nullptr, Mc);
        attn_mfma<<<Bc * NHEAD, 256, 0, stream>>>(q, k, vt, BT, aobf);
        gemm_mfma<1><<<dim3(768 / 128, Gy), 256, 0, stream>>>(
            aobf, wproj, proj_b, nullptr, nullptr, nullptr, nullptr,
            out + (size_t)c * Mc * 768, Mc);
    }
}

// Round 8
// 454.526 us; speedup vs baseline: 1.0422x; 1.0040x over previous
//
#include <hip/hip_runtime.h>
#include <hip/hip_bf16.h>
#include <cstdint>

// Problem constants (ViT-Base, 14x14 window + CLS)
#define BATCH 128
#define NTOK  197
#define NHEAD 12

typedef __attribute__((ext_vector_type(8))) __bf16 bf16x8;
typedef __attribute__((ext_vector_type(4))) float f32x4;
typedef __attribute__((ext_vector_type(4))) unsigned short ushort4v;

#define KSTR 72   // LDS row stride (bf16 elems) for attn P tiles: uniform banks

__device__ __forceinline__ unsigned short f2bf(float f) {
    union { float f; unsigned int u; } v; v.f = f;
    unsigned int r = (v.u + 0x7FFFu + ((v.u >> 16) & 1u)) >> 16;   // RNE
    return (unsigned short)r;
}

// async global->LDS 16B per lane; LDS dest wave-uniform base + lane*16
__device__ __forceinline__ void async_cp16(const void* gsrc, void* lds_dst) {
    __builtin_amdgcn_global_load_lds(
        (const __attribute__((address_space(1))) unsigned int*)((uintptr_t)gsrc),
        (__attribute__((address_space(3))) unsigned int*)((uintptr_t)lds_dst),
        16, 0, 0);
}

// ---------------------------------------------------------------------------
// K0: bias in MFMA C/D fragment order:
//   BT[h][qt16][kt][quad][l16][j*4+r] = rpb[rel_idx[qn][kn]][h]
// Masked keys (kn >= NTOK) get -1e30 so attn's exp() yields 0 directly.
// ---------------------------------------------------------------------------
__global__ void bias_tiles(const float* __restrict__ rpb,
                           const int* __restrict__ rel_idx,
                           float* __restrict__ BT) {
    int idx = blockIdx.x * 256 + threadIdx.x;          // exactly 786432
    int r    = idx & 3;
    int j    = (idx >> 2) & 3;
    int l16  = (idx >> 4) & 15;
    int quad = (idx >> 8) & 3;
    int kt   = (idx >> 10) & 3;
    int qt   = (idx >> 12) & 15;
    int h    = idx >> 16;                              // 0..11
    int qn = qt * 16 + quad * 4 + r; if (qn > 196) qn = 196;
    int kn = kt * 64 + j * 16 + l16;
    float v = -1e30f;
    if (kn < NTOK) v = rpb[rel_idx[qn * NTOK + kn] * NHEAD + h];
    BT[idx] = v;
}

// ---------------------------------------------------------------------------
// fp32 -> bf16 (RNE), vectorized x4
// ---------------------------------------------------------------------------
__global__ __launch_bounds__(256) void cvt_bf16(const float4* __restrict__ src,
                                                ushort4v* __restrict__ dst, int n4) {
    int i = blockIdx.x * 256 + threadIdx.x;
    if (i >= n4) return;
    float4 f = src[i];
    ushort4v o;
    o.x = f2bf(f.x); o.y = f2bf(f.y); o.z = f2bf(f.z); o.w = f2bf(f.w);
    dst[i] = o;
}

// zero helper (vt padding must be 0.0bf16, not uninit bits)
__global__ __launch_bounds__(256) void zero_buf(uint4* __restrict__ p, int n) {
    int i = blockIdx.x * 256 + threadIdx.x;
    if (i < n) p[i] = (uint4){0u, 0u, 0u, 0u};
}

// ---------------------------------------------------------------------------
// bf16 MFMA NT GEMM: 128x128 tile, 4 waves, BK=32, CONFLICT-FREE pair-of-rows
// LDS layout (R7-verified, 0 conflicts) -- NOW DOUBLE-BUFFERED with counted
// vmcnt (m218 lever): prologue stages tiles 0,1; per step:
//   vmcnt(4)  [tile kt landed; kt+1's 4 loads stay in flight]
//   s_barrier -> ds_read frags + 16 MFMA -> lgkmcnt(0) -> s_barrier
//   stage(kt+2) into the buffer just consumed.
// NO __syncthreads() in the loop (it would emit the vmcnt(0) full drain that
// pinned R0/R5/R7 at 19.5% MfmaUtil). Raw barriers + uniform control flow.
// Race-safety: buffer overwritten only after the barrier proving all waves
// read it; reads only after vmcnt proving its loads landed (FIFO, m135).
// + T1 bijective XCD swizzle (R2-verified: FETCH -62%).
// EPI=0: +qkv bias, q*=0.125 -> q,k scatter [Bc,H,N,64]; v -> TRANSPOSED
//        vt [Bc,H,64,256] (tok padded to 256, pad pre-zeroed).
// EPI=1: +proj bias -> fp32 out [m][768]
// ---------------------------------------------------------------------------
template <int EPI>
__global__ __launch_bounds__(256) void gemm_mfma(
    const unsigned short* __restrict__ A,   // [Mc][768] bf16
    const unsigned short* __restrict__ W,   // [Nn][768] bf16
    const float* __restrict__ bias1, const float* __restrict__ bias2,
    unsigned short* __restrict__ oq, unsigned short* __restrict__ ok,
    unsigned short* __restrict__ ov,        // EPI=0: vt [Bc*H*64][256]
    float* __restrict__ outf,
    int Mc) {
    __shared__ unsigned short As[2 * 4096];   // 2 bufs x 8 KiB (pair-of-rows)
    __shared__ unsigned short Bs[2 * 4096];

    const int t    = threadIdx.x;
    const int lane = t & 63;
    const int wave = t >> 6;
    const int wm   = wave >> 1;
    const int wn   = wave & 1;
    const int quad = lane >> 4;
    const int l16  = lane & 15;

    // ---- T1: bijective XCD-aware block swizzle (m204) ----
    const int gx  = gridDim.x;
    const int nwg = gx * gridDim.y;
    const int orig = blockIdx.y * gx + blockIdx.x;
    const int q8 = nwg >> 3, r8 = nwg & 7;
    const int xcd = orig & 7, rest = orig >> 3;
    const int wg = (xcd < r8 ? xcd * (q8 + 1) : r8 * (q8 + 1) + (xcd - r8) * q8) + rest;
    const int m0 = (wg / gx) * 128;
    const int n0 = (wg % gx) * 128;

    // ---- staging lane geometry (R3/R7-verified) ----
    const int grow = wave * 16 + ((lane >> 3) << 1) + ((lane >> 2) & 1);
    const int kcol = (((lane & 3) ^ ((lane >> 3) & 3)) << 3);    // elems
    const unsigned short* Ag[2];
    const unsigned short* Bg[2];
#pragma unroll
    for (int i = 0; i < 2; i++) {
        int ra = m0 + i * 64 + grow; if (ra >= Mc) ra = Mc - 1;
        Ag[i] = A + (size_t)ra * 768 + kcol;
        Bg[i] = W + (size_t)(n0 + i * 64 + grow) * 768 + kcol;
    }

    auto stage = [&](int buf, int kt) {
        const int k0 = kt * 32;
        async_cp16(Ag[0] + k0, As + buf * 4096 + wave * 512);
        async_cp16(Ag[1] + k0, As + buf * 4096 + 2048 + wave * 512);
        async_cp16(Bg[0] + k0, Bs + buf * 4096 + wave * 512);
        async_cp16(Bg[1] + k0, Bs + buf * 4096 + 2048 + wave * 512);
    };

    // ---- frag read offsets (R7-verified pair-of-rows addressing) ----
    const int l2  = l16 >> 1;
    const int par = l16 & 1;
    const int xr  = l2 & 3;
    const int aoff = (wm * 32 + l2) * 64 + par * 32 + ((quad ^ xr) << 3);
    const int boff = (wn * 32 + l2) * 64 + par * 32 + ((quad ^ xr) << 3);

    f32x4 acc[4][4] = {};

    stage(0, 0);
    stage(1, 1);
#pragma unroll 2
    for (int kt = 0; kt < 24; kt++) {
        const int buf = kt & 1;
        if (kt < 23) asm volatile("s_waitcnt vmcnt(4)" ::: "memory");
        else         asm volatile("s_waitcnt vmcnt(0)" ::: "memory");
        __builtin_amdgcn_s_barrier();
        __builtin_amdgcn_sched_barrier(0);

        const unsigned short* Ab = As + buf * 4096 + aoff;
        const unsigned short* Bb = Bs + buf * 4096 + boff;
        bf16x8 af[4], bfr[4];
#pragma unroll
        for (int i = 0; i < 4; i++) af[i]  = *(const bf16x8*)(Ab + i * 512);
#pragma unroll
        for (int j = 0; j < 4; j++) bfr[j] = *(const bf16x8*)(Bb + j * 512);
#pragma unroll
        for (int i = 0; i < 4; i++)
#pragma unroll
            for (int j = 0; j < 4; j++)
                acc[i][j] = __builtin_amdgcn_mfma_f32_16x16x32_bf16(
                    af[i], bfr[j], acc[i][j], 0, 0, 0);

        asm volatile("s_waitcnt lgkmcnt(0)" ::: "memory");   // my reads done
        __builtin_amdgcn_sched_barrier(0);
        __builtin_amdgcn_s_barrier();                        // all waves' reads done
        if (kt < 22) stage(buf, kt + 2);                     // overwrite consumed buf
    }

    // ---- epilogue (R7-verified): C/D col = l16 (n), row = quad*4+r (m) ----
    if (EPI == 0) {
        const int part = n0 / 768;
        const int nb0  = n0 - part * 768;
        const int bi0  = m0 / NTOK;            // block-uniform (scalar)
        const int tk0  = m0 - bi0 * NTOK;
        if (part < 2) {
            const float scale = (part == 0) ? 0.125f : 1.f;
            unsigned short* dst = (part == 0) ? oq : ok;
#pragma unroll
            for (int j = 0; j < 4; j++) {
                const int nnb = nb0 + wn * 64 + j * 16;
                const int h   = nnb >> 6;
                const int d   = (nnb & 63) + l16;
                const float bb = (part == 0) ? bias1[nnb + l16] : 0.f;
#pragma unroll
                for (int i = 0; i < 4; i++) {
                    const int off = wm * 64 + i * 16 + quad * 4;
#pragma unroll
                    for (int r = 0; r < 4; r++) {
                        const int m = m0 + off + r;
                        if (m < Mc) {
                            int tok = tk0 + off + r;
                            int bi  = bi0;
                            if (tok >= NTOK) { tok -= NTOK; bi++; }
                            dst[(((size_t)bi * NHEAD + h) * NTOK + tok) * 64 + d] =
                                f2bf((acc[i][j][r] + bb) * scale);
                        }
                    }
                }
            }
        } else {   // v -> transposed vt[(bi*12+h)*64 + d][256]
#pragma unroll
            for (int j = 0; j < 4; j++) {
                const int nnb = nb0 + wn * 64 + j * 16;
                const int h   = nnb >> 6;
                const int d   = (nnb & 63) + l16;
                const float bb = bias2[nnb + l16];
#pragma unroll
                for (int i = 0; i < 4; i++) {
                    const int off = wm * 64 + i * 16 + quad * 4;
#pragma unroll
                    for (int r = 0; r < 4; r++) {
                        const int m = m0 + off + r;
                        if (m < Mc) {
                            int tok = tk0 + off + r;
                            int bi  = bi0;
                            if (tok >= NTOK) { tok -= NTOK; bi++; }
                            ov[(((size_t)bi * NHEAD + h) * 64 + d) * 256 + tok] =
                                f2bf(acc[i][j][r] + bb);
                        }
                    }
                }
            }
        }
    } else {
#pragma unroll
        for (int j = 0; j < 4; j++) {
            const int col = n0 + wn * 64 + j * 16 + l16;
            const float bb = bias1[col];
#pragma unroll
            for (int i = 0; i < 4; i++) {
                const int mb = m0 + wm * 64 + i * 16 + quad * 4;
#pragma unroll
                for (int r = 0; r < 4; r++) {
                    const int m = mb + r;
                    if (m < Mc) outf[(size_t)m * 768 + col] = acc[i][j][r] + bb;
                }
            }
        }
    }
}

// ---------------------------------------------------------------------------
// K2: MFMA flash attention (R7-verified, unchanged). One block per (b,h);
// 4 waves x 64 q-rows. K/V tiles double-buffered via global_load_lds with
// XOR bank swizzle; V pre-transposed by the QKV GEMM; mask folded into BT.
// ---------------------------------------------------------------------------
__global__ __launch_bounds__(256, 2) void attn_mfma(
    const unsigned short* __restrict__ Q, const unsigned short* __restrict__ K,
    const unsigned short* __restrict__ VT, const float* __restrict__ BT,
    unsigned short* __restrict__ AO) {
    __shared__ unsigned short Ks[2][64 * 64];      // K-tile  [key][d]   (swz)
    __shared__ unsigned short Vt[2][64 * 64];      // V-tile^T [d][key]  (swz)
    __shared__ unsigned short Ps[4][64 * KSTR];    // per-wave P [q][key]

    const int t    = threadIdx.x;
    const int lane = t & 63;
    const int wave = t >> 6;
    const int quad = lane >> 4;
    const int l16  = lane & 15;
    const int bh   = blockIdx.x;
    const int b    = bh / NHEAD;
    const int h    = bh - b * NHEAD;

    const unsigned short* qb  = Q  + (size_t)bh * NTOK * 64;
    const unsigned short* kb  = K  + (size_t)bh * NTOK * 64;
    const unsigned short* vtg = VT + (size_t)bh * 64 * 256;

    // staging lane geometry (R5-verified)
    const int rsub = wave * 8 + (lane >> 3);
    const int chk  = ((lane & 7) ^ (lane >> 3)) * 8;         // elems

    auto stage = [&](int buf, int kt) {
        int gk0 = kt * 64 + rsub;      if (gk0 > 196) gk0 = 196;
        int gk1 = kt * 64 + 32 + rsub; if (gk1 > 196) gk1 = 196;
        async_cp16(kb + (size_t)gk0 * 64 + chk, Ks[buf] + wave * 512);
        async_cp16(kb + (size_t)gk1 * 64 + chk, Ks[buf] + 2048 + wave * 512);
        async_cp16(vtg + (size_t)rsub * 256 + kt * 64 + chk, Vt[buf] + wave * 512);
        async_cp16(vtg + (size_t)(32 + rsub) * 256 + kt * 64 + chk,
                   Vt[buf] + 2048 + wave * 512);
    };

    // Q fragments in registers for the whole kernel (A-layout: m=l16, k=quad*8+j)
    bf16x8 qf[4][2];
#pragma unroll
    for (int i = 0; i < 4; i++) {
        int tok = wave * 64 + i * 16 + l16; if (tok > 196) tok = 196;
#pragma unroll
        for (int ks = 0; ks < 2; ks++)
            qf[i][ks] = *(const bf16x8*)&qb[(size_t)tok * 64 + ks * 32 + quad * 8];
    }

    f32x4 O[4][4] = {};
    float lsum[4][4] = {};        // [i][r]

    stage(0, 0);
    asm volatile("s_waitcnt vmcnt(0)" ::: "memory");
    __builtin_amdgcn_s_barrier();

    for (int kt = 0; kt < 4; kt++) {
        const int buf = kt & 1;

        // ---- acc init = rpb fragments ----
        f32x4 acc[4][4];
#pragma unroll
        for (int i = 0; i < 4; i++) {
            const float4* bp = (const float4*)&BT[
                (((((size_t)h * 16 + (wave * 4 + i)) * 4 + kt) * 4 + quad) * 16 + l16) * 16];
#pragma unroll
            for (int j = 0; j < 4; j++) {
                float4 f = bp[j];
                acc[i][j] = (f32x4){f.x, f.y, f.z, f.w};
            }
        }

        if (kt < 3) stage(buf ^ 1, kt + 1);   // prefetch under this tile's compute

        // ---- S = q.k^T + bias ----
#pragma unroll
        for (int ks = 0; ks < 2; ks++) {
            bf16x8 kf[4];
#pragma unroll
            for (int j = 0; j < 4; j++)
                kf[j] = *(const bf16x8*)&Ks[buf][(j * 16 + l16) * 64 +
                                               (((ks * 4 + quad) ^ (l16 & 7)) * 8)];
            __builtin_amdgcn_s_setprio(1);
#pragma unroll
            for (int i = 0; i < 4; i++)
#pragma unroll
                for (int j = 0; j < 4; j++)
                    acc[i][j] = __builtin_amdgcn_mfma_f32_16x16x32_bf16(
                        qf[i][ks], kf[j], acc[i][j], 0, 0, 0);
            __builtin_amdgcn_s_setprio(0);
        }

        // ---- fixed-max softmax: p = exp(s) (mask folded into BT) ----
#pragma unroll
        for (int j = 0; j < 4; j++)
#pragma unroll
            for (int i = 0; i < 4; i++)
#pragma unroll
                for (int r = 0; r < 4; r++) {
                    float p = __expf(fminf(acc[i][j][r], 30.f));
                    lsum[i][r] += p;
                    Ps[wave][(i * 16 + quad * 4 + r) * KSTR + j * 16 + l16] = f2bf(p);
                }

        // ---- O += P.V ----
#pragma unroll
        for (int ks = 0; ks < 2; ks++) {
            bf16x8 vf[4], pf[4];
#pragma unroll
            for (int jd = 0; jd < 4; jd++)
                vf[jd] = *(const bf16x8*)&Vt[buf][(jd * 16 + l16) * 64 +
                                                 (((ks * 4 + quad) ^ (l16 & 7)) * 8)];
#pragma unroll
            for (int i = 0; i < 4; i++)
                pf[i] = *(const bf16x8*)&Ps[wave][(i * 16 + l16) * KSTR + ks * 32 + quad * 8];
            __builtin_amdgcn_s_setprio(1);
#pragma unroll
            for (int i = 0; i < 4; i++)
#pragma unroll
                for (int jd = 0; jd < 4; jd++)
                    O[i][jd] = __builtin_amdgcn_mfma_f32_16x16x32_bf16(
                        pf[i], vf[jd], O[i][jd], 0, 0, 0);
            __builtin_amdgcn_s_setprio(0);
        }

        // tile boundary: prefetch (issued ~2000 cyc ago) lands; buffers swap
        asm volatile("s_waitcnt vmcnt(0)" ::: "memory");
        __builtin_amdgcn_s_barrier();
    }

    // ---- l-sum reduction across the 16-lane col groups, then store ----
#pragma unroll
    for (int i = 0; i < 4; i++)
#pragma unroll
        for (int r = 0; r < 4; r++) {
            float l = lsum[i][r];
            l += __shfl_xor(l, 1); l += __shfl_xor(l, 2);
            l += __shfl_xor(l, 4); l += __shfl_xor(l, 8);
            lsum[i][r] = 1.f / l;
        }
#pragma unroll
    for (int i = 0; i < 4; i++) {
        const int tb = wave * 64 + i * 16 + quad * 4;
#pragma unroll
        for (int r = 0; r < 4; r++) {
            const int tok = tb + r;
            if (tok < NTOK) {
                const float rl = lsum[i][r];
#pragma unroll
                for (int jd = 0; jd < 4; jd++)
                    AO[((size_t)b * NTOK + tok) * 768 + h * 64 + jd * 16 + l16] =
                        f2bf(O[i][jd][r] * rl);
            }
        }
    }
}

// ---------------------------------------------------------------------------
extern "C" void kernel_launch(void* const* d_in, const int* in_sizes, int n_in,
                              void* d_out, int out_size, void* d_ws, size_t ws_size,
                              hipStream_t stream) {
    const float* x      = (const float*)d_in[0];
    const float* qkv_w  = (const float*)d_in[1];
    const float* q_bias = (const float*)d_in[2];
    const float* v_bias = (const float*)d_in[3];
    const float* rpb    = (const float*)d_in[4];
    const float* proj_w = (const float*)d_in[5];
    const float* proj_b = (const float*)d_in[6];
    const int*   rel_idx = (const int*)d_in[7];
    float* out = (float*)d_out;

    const size_t EB   = 151296;                    // 12*197*64 = 197*768
    const size_t VTE  = 196608;                    // 12*64*256 (vt elems/batch)
    const size_t NBT  = 786432;                    // bias tiles (floats)
    const size_t NX   = (size_t)BATCH * NTOK * 768;
    const size_t NWQ  = (size_t)2304 * 768;
    const size_t NWP  = (size_t)768 * 768;

    // layout: BT(f32) | xbf | wqkv | wproj | q,k (EB) | vt (VTE) | ao (EB)
    const size_t fixed_bytes = NBT * 4 + (NX + NWQ + NWP) * 2;
    const size_t per_b = 2ull * (3 * EB + VTE);    // bytes per batch elem
    int Bc = BATCH;
    while (Bc > 1 && fixed_bytes + (size_t)Bc * per_b > ws_size) Bc >>= 1;
    if (fixed_bytes + (size_t)Bc * per_b > ws_size) return;
    const int nc = BATCH / Bc;
    const int Mc = Bc * NTOK;
    const int Gy = (Mc + 127) / 128;

    float* BT             = (float*)d_ws;
    unsigned short* xbf   = (unsigned short*)(BT + NBT);
    unsigned short* wqkv  = xbf + NX;
    unsigned short* wproj = wqkv + NWQ;
    unsigned short* q     = wproj + NWP;
    unsigned short* k     = q + (size_t)Bc * EB;
    unsigned short* vt    = k + (size_t)Bc * EB;
    unsigned short* aobf  = vt + (size_t)Bc * VTE;

    const int nz = Bc * 24576;                     // vt bytes / 16
    zero_buf<<<(nz + 255) / 256, 256, 0, stream>>>((uint4*)vt, nz);
    bias_tiles<<<(int)(NBT / 256), 256, 0, stream>>>(rpb, rel_idx, BT);
    cvt_bf16<<<(int)((NX / 4 + 255) / 256), 256, 0, stream>>>(
        (const float4*)x, (ushort4v*)xbf, (int)(NX / 4));
    cvt_bf16<<<(int)((NWQ / 4 + 255) / 256), 256, 0, stream>>>(
        (const float4*)qkv_w, (ushort4v*)wqkv, (int)(NWQ / 4));
    cvt_bf16<<<(int)((NWP / 4 + 255) / 256), 256, 0, stream>>>(
        (const float4*)proj_w, (ushort4v*)wproj, (int)(NWP / 4));

    for (int c = 0; c < nc; c++) {
        gemm_mfma<0><<<dim3(2304 / 128, Gy), 256, 0, stream>>>(
            xbf + (size_t)c * Mc * 768, wqkv, q_bias, v_bias, q, k, vt, nullptr, Mc);
        attn_mfma<<<Bc * NHEAD, 256, 0, stream>>>(q, k, vt, BT, aobf);
        gemm_mfma<1><<<dim3(768 / 128, Gy), 256, 0, stream>>>(
            aobf, wproj, proj_b, nullptr, nullptr, nullptr, nullptr,
            out + (size_t)c * Mc * 768, Mc);
    }
}